// Round 1
// baseline (252.181 us; speedup 1.0000x reference)
//
#include <hip/hip_runtime.h>
#include <cfloat>
#include <cstdint>
#include <cstddef>

using u16 = unsigned short;
typedef __attribute__((ext_vector_type(8))) short short8;
typedef __attribute__((ext_vector_type(4))) float f32x4;

#define HEADS 6
#define NSEQ 4096
#define SCALEF 0.125f

__device__ __forceinline__ u16 f2bf_rn(float f) {
  unsigned int u = __builtin_bit_cast(unsigned int, f);
  u = (u + 0x7FFFu + ((u >> 16) & 1u)) >> 16;
  return (u16)u;
}

__device__ __forceinline__ void gload_lds16(const void* g, void* l) {
  __builtin_amdgcn_global_load_lds((const __attribute__((address_space(1))) void*)g,
                                   (__attribute__((address_space(3))) void*)l, 16, 0, 0);
}

// Swizzled b128 read from a [rows][64] u16 LDS tile (128B rows).
// Swizzle: 16B-block index ^= (row&7)  (involution; matches staging source perm)
__device__ __forceinline__ short8 frag_read(const u16* tile, int row, int blk) {
  int byt = row * 128 + ((blk * 16) ^ ((row & 7) << 4));
  return *(const short8*)((const char*)tile + byt);
}

__global__ void cast_kernel(const float* __restrict__ src, u16* __restrict__ dst, int n8) {
  int i = blockIdx.x * blockDim.x + threadIdx.x;
  if (i >= n8) return;
  const float4* s = (const float4*)src;
  float4 a = s[2 * i], b = s[2 * i + 1];
  short8 r;
  r[0] = (short)f2bf_rn(a.x); r[1] = (short)f2bf_rn(a.y);
  r[2] = (short)f2bf_rn(a.z); r[3] = (short)f2bf_rn(a.w);
  r[4] = (short)f2bf_rn(b.x); r[5] = (short)f2bf_rn(b.y);
  r[6] = (short)f2bf_rn(b.z); r[7] = (short)f2bf_rn(b.w);
  ((short8*)dst)[i] = r;
}

// C = A(MxK) * B(NxK)^T ; 128x128 tile, BK=64, 4 waves (2x2 of 64x64).
// EPI 0: scatter qkv -> q[b,h,n,d], k[b,h,n,d], vT[b,h,d,n] (bf16)
// EPI 1: out = C + bias (fp32)
template <int EPI>
__launch_bounds__(256)
__global__ void gemm_bt(const u16* __restrict__ A, const u16* __restrict__ B,
                        int Kdim, int Ndim,
                        u16* __restrict__ q_out, u16* __restrict__ k_out, u16* __restrict__ vt_out,
                        const float* __restrict__ bias, float* __restrict__ out) {
  __shared__ u16 lA[128 * 64];
  __shared__ u16 lB[128 * 64];
  int brow = blockIdx.x, bcol = blockIdx.y;
  int tid = threadIdx.x;
  int w = tid >> 6, lane = tid & 63;
  int wr = w >> 1, wc = w & 1;
  int r_in = lane >> 3;
  int jblk = (lane & 7) ^ r_in;  // pre-swizzled global 16B-block (involution with frag_read)
  int l15 = lane & 15, lg = lane >> 4;

  f32x4 acc[4][4];
#pragma unroll
  for (int i = 0; i < 4; i++)
#pragma unroll
    for (int j = 0; j < 4; j++) acc[i][j] = (f32x4){0.f, 0.f, 0.f, 0.f};

  const u16* Ab = A + (size_t)(brow * 128 + w * 32 + r_in) * Kdim + jblk * 8;
  const u16* Bb = B + (size_t)(bcol * 128 + w * 32 + r_in) * Kdim + jblk * 8;

  int ksteps = Kdim >> 6;
  for (int kt = 0; kt < ksteps; ++kt) {
    __syncthreads();
#pragma unroll
    for (int c = 0; c < 4; ++c) {
      gload_lds16(Ab + kt * 64 + (size_t)(c * 8) * Kdim, &lA[(w * 32 + c * 8) * 64]);
      gload_lds16(Bb + kt * 64 + (size_t)(c * 8) * Kdim, &lB[(w * 32 + c * 8) * 64]);
    }
    asm volatile("s_waitcnt vmcnt(0)" ::: "memory");
    __syncthreads();

    short8 af[4][2], bfr[4][2];
#pragma unroll
    for (int ms = 0; ms < 4; ++ms)
#pragma unroll
      for (int hf = 0; hf < 2; ++hf)
        af[ms][hf] = frag_read(lA, wr * 64 + ms * 16 + l15, hf * 4 + lg);
#pragma unroll
    for (int ns = 0; ns < 4; ++ns)
#pragma unroll
      for (int hf = 0; hf < 2; ++hf)
        bfr[ns][hf] = frag_read(lB, wc * 64 + ns * 16 + l15, hf * 4 + lg);
#pragma unroll
    for (int ms = 0; ms < 4; ++ms)
#pragma unroll
      for (int ns = 0; ns < 4; ++ns) {
        acc[ms][ns] = __builtin_amdgcn_mfma_f32_16x16x32_bf16(af[ms][0], bfr[ns][0], acc[ms][ns], 0, 0, 0);
        acc[ms][ns] = __builtin_amdgcn_mfma_f32_16x16x32_bf16(af[ms][1], bfr[ns][1], acc[ms][ns], 0, 0, 0);
      }
  }

#pragma unroll
  for (int ms = 0; ms < 4; ++ms)
#pragma unroll
    for (int ns = 0; ns < 4; ++ns)
#pragma unroll
      for (int r = 0; r < 4; ++r) {
        int row_g = brow * 128 + wr * 64 + ms * 16 + lg * 4 + r;
        int col_g = bcol * 128 + wc * 64 + ns * 16 + l15;
        float v = acc[ms][ns][r];
        if (EPI == 0) {
          int t = col_g / 384;
          int rem = col_g - t * 384;
          int h = rem >> 6, d = rem & 63;
          int b = row_g >> 12, n = row_g & 4095;
          u16 val = f2bf_rn(v);
          size_t bh = (size_t)(b * HEADS + h);
          if (t == 0)      q_out[(bh * NSEQ + n) * 64 + d] = val;
          else if (t == 1) k_out[(bh * NSEQ + n) * 64 + d] = val;
          else             vt_out[(bh * 64 + d) * NSEQ + n] = val;
        } else {
          out[(size_t)row_g * Ndim + col_g] = v + bias[col_g];
        }
      }
}

// Flash attention: block = 128 threads (2 waves x 32 q-rows), KT=64.
__launch_bounds__(128)
__global__ void attn_kernel(const u16* __restrict__ qg, const u16* __restrict__ kg,
                            const u16* __restrict__ vtg, const int* __restrict__ mask,
                            u16* __restrict__ attn_out) {
  __shared__ u16 lK[64 * 64];      // [k_seq][d], swizzled
  __shared__ u16 lV[64 * 64];      // [d][k_seq], swizzled
  __shared__ u16 lP[2][32 * 64];   // per wave [q_local][k_local], swizzled

  int bh = blockIdx.y;
  int b = bh / HEADS, h = bh - b * HEADS;
  int q0 = blockIdx.x * 64;
  int tid = threadIdx.x;
  int w = tid >> 6, lane = tid & 63;
  int l15 = lane & 15, lg = lane >> 4;
  int r_in = lane >> 3, jblk = (lane & 7) ^ r_in;

  const u16* Q = qg + (size_t)bh * NSEQ * 64;
  const u16* K = kg + (size_t)bh * NSEQ * 64;
  const u16* VT = vtg + (size_t)bh * 64 * NSEQ;
  const int* mrow = mask + b * NSEQ;

  // Q fragments hoisted to registers: rows q0+w*32+rs*16+l15, k = hf*32+lg*8
  short8 qf[2][2];
#pragma unroll
  for (int rs = 0; rs < 2; ++rs)
#pragma unroll
    for (int hf = 0; hf < 2; ++hf)
      qf[rs][hf] = *(const short8*)(Q + (size_t)(q0 + w * 32 + rs * 16 + l15) * 64 + hf * 32 + lg * 8);

  bool mq[2][4];
#pragma unroll
  for (int rs = 0; rs < 2; ++rs)
#pragma unroll
    for (int r = 0; r < 4; ++r)
      mq[rs][r] = mrow[q0 + w * 32 + rs * 16 + lg * 4 + r] != 0;

  f32x4 O[2][4];
  float m_r[2][4], l_r[2][4];
#pragma unroll
  for (int rs = 0; rs < 2; ++rs)
#pragma unroll
    for (int r = 0; r < 4; ++r) {
      m_r[rs][r] = -INFINITY;
      l_r[rs][r] = 0.f;
    }
#pragma unroll
  for (int rs = 0; rs < 2; ++rs)
#pragma unroll
    for (int ds_ = 0; ds_ < 4; ++ds_) O[rs][ds_] = (f32x4){0.f, 0.f, 0.f, 0.f};

  for (int t = 0; t < NSEQ / 64; ++t) {
    int k0 = t * 64;
    __syncthreads();
#pragma unroll
    for (int c = 0; c < 4; ++c) {
      int rowb = w * 32 + c * 8;
      gload_lds16(K + (size_t)(k0 + rowb + r_in) * 64 + jblk * 8, &lK[rowb * 64]);
      gload_lds16(VT + (size_t)(rowb + r_in) * NSEQ + k0 + jblk * 8, &lV[rowb * 64]);
    }
    asm volatile("s_waitcnt vmcnt(0)" ::: "memory");
    __syncthreads();

    // S = Q K^T  (D rows = q, cols = k_seq)
    f32x4 S[2][4];
#pragma unroll
    for (int cs = 0; cs < 4; ++cs) {
      short8 kf0 = frag_read(lK, cs * 16 + l15, lg);
      short8 kf1 = frag_read(lK, cs * 16 + l15, 4 + lg);
#pragma unroll
      for (int rs = 0; rs < 2; ++rs) {
        f32x4 z = (f32x4){0.f, 0.f, 0.f, 0.f};
        z = __builtin_amdgcn_mfma_f32_16x16x32_bf16(qf[rs][0], kf0, z, 0, 0, 0);
        S[rs][cs] = __builtin_amdgcn_mfma_f32_16x16x32_bf16(qf[rs][1], kf1, z, 0, 0, 0);
      }
    }

    int mkc[4];
#pragma unroll
    for (int cs = 0; cs < 4; ++cs) mkc[cs] = mrow[k0 + cs * 16 + l15];

    // online softmax (fp32), P -> per-wave LDS (bf16, swizzled)
#pragma unroll
    for (int rs = 0; rs < 2; ++rs) {
#pragma unroll
      for (int r = 0; r < 4; ++r) {
        float v0 = (mkc[0] && mq[rs][r]) ? S[rs][0][r] * SCALEF : -FLT_MAX;
        float v1 = (mkc[1] && mq[rs][r]) ? S[rs][1][r] * SCALEF : -FLT_MAX;
        float v2 = (mkc[2] && mq[rs][r]) ? S[rs][2][r] * SCALEF : -FLT_MAX;
        float v3 = (mkc[3] && mq[rs][r]) ? S[rs][3][r] * SCALEF : -FLT_MAX;
        float tmax = fmaxf(fmaxf(v0, v1), fmaxf(v2, v3));
#pragma unroll
        for (int off = 1; off < 16; off <<= 1) tmax = fmaxf(tmax, __shfl_xor(tmax, off));
        float mold = m_r[rs][r];
        float mnew = fmaxf(mold, tmax);
        float corr = __expf(mold - mnew);
        m_r[rs][r] = mnew;
        float p0 = __expf(v0 - mnew);
        float p1 = __expf(v1 - mnew);
        float p2 = __expf(v2 - mnew);
        float p3 = __expf(v3 - mnew);
        float rsum = p0 + p1 + p2 + p3;
#pragma unroll
        for (int off = 1; off < 16; off <<= 1) rsum += __shfl_xor(rsum, off);
        l_r[rs][r] = l_r[rs][r] * corr + rsum;
#pragma unroll
        for (int ds_ = 0; ds_ < 4; ++ds_) O[rs][ds_][r] *= corr;

        int prow = rs * 16 + lg * 4 + r;
        int rsw = (prow & 7) << 4;
        char* pb = (char*)lP[w] + prow * 128;
        *(u16*)(pb + ((0 * 32 + l15 * 2) ^ rsw)) = f2bf_rn(p0);
        *(u16*)(pb + ((1 * 32 + l15 * 2) ^ rsw)) = f2bf_rn(p1);
        *(u16*)(pb + ((2 * 32 + l15 * 2) ^ rsw)) = f2bf_rn(p2);
        *(u16*)(pb + ((3 * 32 + l15 * 2) ^ rsw)) = f2bf_rn(p3);
      }
    }

    // O += P V   (B-frags straight from V^T tile)
    short8 vf[4][2];
#pragma unroll
    for (int ds_ = 0; ds_ < 4; ++ds_) {
      vf[ds_][0] = frag_read(lV, ds_ * 16 + l15, lg);
      vf[ds_][1] = frag_read(lV, ds_ * 16 + l15, 4 + lg);
    }
#pragma unroll
    for (int rs = 0; rs < 2; ++rs) {
      short8 pf0 = frag_read(lP[w], rs * 16 + l15, lg);
      short8 pf1 = frag_read(lP[w], rs * 16 + l15, 4 + lg);
#pragma unroll
      for (int ds_ = 0; ds_ < 4; ++ds_) {
        O[rs][ds_] = __builtin_amdgcn_mfma_f32_16x16x32_bf16(pf0, vf[ds_][0], O[rs][ds_], 0, 0, 0);
        O[rs][ds_] = __builtin_amdgcn_mfma_f32_16x16x32_bf16(pf1, vf[ds_][1], O[rs][ds_], 0, 0, 0);
      }
    }
  }

  // epilogue: attn_out[b, n, h*64+d] = O / l  (bf16)
#pragma unroll
  for (int rs = 0; rs < 2; ++rs)
#pragma unroll
    for (int r = 0; r < 4; ++r) {
      float inv = 1.0f / l_r[rs][r];
      int n = q0 + w * 32 + rs * 16 + lg * 4 + r;
#pragma unroll
      for (int ds_ = 0; ds_ < 4; ++ds_) {
        int d = ds_ * 16 + l15;
        attn_out[((size_t)b * NSEQ + n) * 384 + h * 64 + d] = f2bf_rn(O[rs][ds_][r] * inv);
      }
    }
}

extern "C" void kernel_launch(void* const* d_in, const int* in_sizes, int n_in,
                              void* d_out, int out_size, void* d_ws, size_t ws_size,
                              hipStream_t stream) {
  const float* x = (const float*)d_in[0];
  const int* mask = (const int*)d_in[1];
  const float* w_qkv = (const float*)d_in[2];
  const float* w_proj = (const float*)d_in[3];
  const float* b_proj = (const float*)d_in[4];
  float* out = (float*)d_out;

  char* ws = (char*)d_ws;
  u16* x_bf = (u16*)(ws + 0);              //  8192x384
  u16* wqkv_bf = (u16*)(ws + 6291456);     //  1152x384
  u16* wproj_bf = (u16*)(ws + 7176192);    //   384x384
  u16* q_bf = (u16*)(ws + 7471104);        //  [b,h,n,d]
  u16* k_bf = (u16*)(ws + 13762560);       //  [b,h,n,d]
  u16* vt_bf = (u16*)(ws + 20054016);      //  [b,h,d,n]
  u16* attn_bf = (u16*)(ws + 26345472);    //  8192x384

  cast_kernel<<<(3145728 / 8 + 255) / 256, 256, 0, stream>>>(x, x_bf, 3145728 / 8);
  cast_kernel<<<(442368 / 8 + 255) / 256, 256, 0, stream>>>(w_qkv, wqkv_bf, 442368 / 8);
  cast_kernel<<<(147456 / 8 + 255) / 256, 256, 0, stream>>>(w_proj, wproj_bf, 147456 / 8);

  gemm_bt<0><<<dim3(64, 9), 256, 0, stream>>>(x_bf, wqkv_bf, 384, 1152,
                                              q_bf, k_bf, vt_bf, nullptr, nullptr);
  attn_kernel<<<dim3(64, 12), 128, 0, stream>>>(q_bf, k_bf, vt_bf, mask, attn_bf);
  gemm_bt<1><<<dim3(64, 3), 256, 0, stream>>>(attn_bf, wproj_bf, 384, 384,
                                              nullptr, nullptr, nullptr, b_proj, out);
}

// Round 2
// 153.810 us; speedup vs baseline: 1.6396x; 1.6396x over previous
//
#include <hip/hip_runtime.h>
#include <cfloat>
#include <cstdint>
#include <cstddef>

using u16 = unsigned short;
typedef __attribute__((ext_vector_type(8))) short short8;
typedef __attribute__((ext_vector_type(4))) float f32x4;

#define HEADS 6
#define NSEQ 4096
#define SCALEF 0.125f
#define LOG2E 1.4426950408889634f
#define SC2 (SCALEF * LOG2E)

#if __has_builtin(__builtin_amdgcn_exp2f)
#define EXP2(x) __builtin_amdgcn_exp2f(x)
#else
#define EXP2(x) exp2f(x)
#endif

__device__ __forceinline__ u16 f2bf_rn(float f) {
  unsigned int u = __builtin_bit_cast(unsigned int, f);
  u = (u + 0x7FFFu + ((u >> 16) & 1u)) >> 16;
  return (u16)u;
}

__device__ __forceinline__ void gload_lds16(const void* g, void* l) {
  __builtin_amdgcn_global_load_lds((const __attribute__((address_space(1))) void*)g,
                                   (__attribute__((address_space(3))) void*)l, 16, 0, 0);
}

// Swizzled b128 read from a [rows][64] u16 LDS tile (128B rows).
__device__ __forceinline__ short8 frag_read(const u16* tile, int row, int blk) {
  int byt = row * 128 + ((blk * 16) ^ ((row & 7) << 4));
  return *(const short8*)((const char*)tile + byt);
}

__global__ void cast_kernel(const float* __restrict__ src, u16* __restrict__ dst, int n8) {
  int i = blockIdx.x * blockDim.x + threadIdx.x;
  if (i >= n8) return;
  const float4* s = (const float4*)src;
  float4 a = s[2 * i], b = s[2 * i + 1];
  short8 r;
  r[0] = (short)f2bf_rn(a.x); r[1] = (short)f2bf_rn(a.y);
  r[2] = (short)f2bf_rn(a.z); r[3] = (short)f2bf_rn(a.w);
  r[4] = (short)f2bf_rn(b.x); r[5] = (short)f2bf_rn(b.y);
  r[6] = (short)f2bf_rn(b.z); r[7] = (short)f2bf_rn(b.w);
  ((short8*)dst)[i] = r;
}

// C = A(MxK) * B(NxK)^T ; 128x128 tile, BK=64, 4 waves (2x2 of 64x64).
template <int EPI>
__launch_bounds__(256)
__global__ void gemm_bt(const u16* __restrict__ A, const u16* __restrict__ B,
                        int Kdim, int Ndim,
                        u16* __restrict__ q_out, u16* __restrict__ k_out, u16* __restrict__ vt_out,
                        const float* __restrict__ bias, float* __restrict__ out) {
  __shared__ u16 lA[128 * 64];
  __shared__ u16 lB[128 * 64];
  int brow = blockIdx.x, bcol = blockIdx.y;
  int tid = threadIdx.x;
  int w = tid >> 6, lane = tid & 63;
  int wr = w >> 1, wc = w & 1;
  int r_in = lane >> 3;
  int jblk = (lane & 7) ^ r_in;
  int l15 = lane & 15, lg = lane >> 4;

  f32x4 acc[4][4];
#pragma unroll
  for (int i = 0; i < 4; i++)
#pragma unroll
    for (int j = 0; j < 4; j++) acc[i][j] = (f32x4){0.f, 0.f, 0.f, 0.f};

  const u16* Ab = A + (size_t)(brow * 128 + w * 32 + r_in) * Kdim + jblk * 8;
  const u16* Bb = B + (size_t)(bcol * 128 + w * 32 + r_in) * Kdim + jblk * 8;

  int ksteps = Kdim >> 6;
  for (int kt = 0; kt < ksteps; ++kt) {
    __syncthreads();
#pragma unroll
    for (int c = 0; c < 4; ++c) {
      gload_lds16(Ab + kt * 64 + (size_t)(c * 8) * Kdim, &lA[(w * 32 + c * 8) * 64]);
      gload_lds16(Bb + kt * 64 + (size_t)(c * 8) * Kdim, &lB[(w * 32 + c * 8) * 64]);
    }
    asm volatile("s_waitcnt vmcnt(0)" ::: "memory");
    __syncthreads();

    short8 af[4][2], bfr[4][2];
#pragma unroll
    for (int ms = 0; ms < 4; ++ms)
#pragma unroll
      for (int hf = 0; hf < 2; ++hf)
        af[ms][hf] = frag_read(lA, wr * 64 + ms * 16 + l15, hf * 4 + lg);
#pragma unroll
    for (int ns = 0; ns < 4; ++ns)
#pragma unroll
      for (int hf = 0; hf < 2; ++hf)
        bfr[ns][hf] = frag_read(lB, wc * 64 + ns * 16 + l15, hf * 4 + lg);
#pragma unroll
    for (int ms = 0; ms < 4; ++ms)
#pragma unroll
      for (int ns = 0; ns < 4; ++ns) {
        acc[ms][ns] = __builtin_amdgcn_mfma_f32_16x16x32_bf16(af[ms][0], bfr[ns][0], acc[ms][ns], 0, 0, 0);
        acc[ms][ns] = __builtin_amdgcn_mfma_f32_16x16x32_bf16(af[ms][1], bfr[ns][1], acc[ms][ns], 0, 0, 0);
      }
  }

#pragma unroll
  for (int ms = 0; ms < 4; ++ms)
#pragma unroll
    for (int ns = 0; ns < 4; ++ns)
#pragma unroll
      for (int r = 0; r < 4; ++r) {
        int row_g = brow * 128 + wr * 64 + ms * 16 + lg * 4 + r;
        int col_g = bcol * 128 + wc * 64 + ns * 16 + l15;
        float v = acc[ms][ns][r];
        if (EPI == 0) {
          int t = col_g / 384;
          int rem = col_g - t * 384;
          int h = rem >> 6, d = rem & 63;
          int b = row_g >> 12, n = row_g & 4095;
          u16 val = f2bf_rn(v);
          size_t bh = (size_t)(b * HEADS + h);
          if (t == 0)      q_out[(bh * NSEQ + n) * 64 + d] = val;
          else if (t == 1) k_out[(bh * NSEQ + n) * 64 + d] = val;
          else             vt_out[(bh * 64 + d) * NSEQ + n] = val;
        } else {
          out[(size_t)row_g * Ndim + col_g] = v + bias[col_g];
        }
      }
}

// Flash attention, swapped-operand (T12): 256 thr = 4 waves x 16 q-rows, KT=64.
// All softmax state lane-local (q = l15); P^T -> PV B-frags via permlane swaps.
__launch_bounds__(256, 3)
__global__ void attn_kernel(const u16* __restrict__ qg, const u16* __restrict__ kg,
                            const u16* __restrict__ vtg, const int* __restrict__ mask,
                            u16* __restrict__ attn_out) {
  __shared__ u16 lK[2][64 * 64];   // [k_seq][d], swizzled
  __shared__ u16 lV[2][64 * 64];   // [d][k_seq], swizzled

  // bijective XCD swizzle: 768 blocks, 96 per XCD, contiguous bh-major work per XCD
  int bid = blockIdx.y * 64 + blockIdx.x;
  int orig = (bid & 7) * 96 + (bid >> 3);
  int qb = orig & 63, bh = orig >> 6;

  int b = bh / HEADS, h = bh - b * HEADS;
  int q0 = qb * 64;
  int tid = threadIdx.x;
  int w = tid >> 6, lane = tid & 63;
  int l15 = lane & 15, lg = lane >> 4;
  int r_in = lane >> 3, jblk = (lane & 7) ^ r_in;

  const u16* Q = qg + (size_t)bh * NSEQ * 64;
  const u16* K = kg + (size_t)bh * NSEQ * 64;
  const u16* VT = vtg + (size_t)bh * 64 * NSEQ;
  const int* mrow = mask + b * NSEQ;

  int qrow = q0 + w * 16 + l15;
  // Q fragment (B-operand): lane holds Q[qrow][hf*32 + lg*8 + j]
  short8 qf[2];
#pragma unroll
  for (int hf = 0; hf < 2; ++hf)
    qf[hf] = *(const short8*)(Q + (size_t)qrow * 64 + hf * 32 + lg * 8);

  float aqf = mrow[qrow] ? 0.f : -FLT_MAX;

  f32x4 acc[4];  // O^T: acc[ds][r] = O[d = ds*16 + lg*4 + r][q = qrow]
#pragma unroll
  for (int ds_ = 0; ds_ < 4; ++ds_) acc[ds_] = (f32x4){0.f, 0.f, 0.f, 0.f};
  float m2 = -INFINITY, l_r = 0.f;

#define STAGE(buf, t)                                                                   \
  {                                                                                     \
    int k0s = (t) * 64;                                                                 \
    _Pragma("unroll")                                                                   \
    for (int c = 0; c < 2; ++c) {                                                       \
      int rowb = w * 16 + c * 8;                                                        \
      gload_lds16(K + (size_t)(k0s + rowb + r_in) * 64 + jblk * 8, &lK[buf][rowb * 64]);\
      gload_lds16(VT + (size_t)(rowb + r_in) * NSEQ + k0s + jblk * 8, &lV[buf][rowb * 64]);\
    }                                                                                   \
  }

  STAGE(0, 0);
  __syncthreads();

  const int NT = NSEQ / 64;
  int cur = 0;
  for (int t = 0; t < NT; ++t) {
    if (t + 1 < NT) STAGE(cur ^ 1, t + 1);
    int k0 = t * 64;

    // mask addends: addn[cs][r] for k = k0 + cs*16 + lg*4 + r
    f32x4 addn[4];
#pragma unroll
    for (int cs = 0; cs < 4; ++cs) {
      int4 mk = *(const int4*)(mrow + k0 + cs * 16 + lg * 4);
      addn[cs][0] = mk.x ? aqf : -FLT_MAX;
      addn[cs][1] = mk.y ? aqf : -FLT_MAX;
      addn[cs][2] = mk.z ? aqf : -FLT_MAX;
      addn[cs][3] = mk.w ? aqf : -FLT_MAX;
    }

    // S^T = K Q^T : p[cs][r] = S[q = qrow][k = k0 + cs*16 + lg*4 + r]
    f32x4 p[4];
    __builtin_amdgcn_s_setprio(1);
#pragma unroll
    for (int cs = 0; cs < 4; ++cs) {
      short8 kf0 = frag_read(lK[cur], cs * 16 + l15, lg);
      short8 kf1 = frag_read(lK[cur], cs * 16 + l15, 4 + lg);
      f32x4 z = (f32x4){0.f, 0.f, 0.f, 0.f};
      z = __builtin_amdgcn_mfma_f32_16x16x32_bf16(kf0, qf[0], z, 0, 0, 0);
      p[cs] = __builtin_amdgcn_mfma_f32_16x16x32_bf16(kf1, qf[1], z, 0, 0, 0);
    }
    __builtin_amdgcn_s_setprio(0);

    // ppre = s*SCALE*log2e + addend  (log2 space)
#pragma unroll
    for (int cs = 0; cs < 4; ++cs)
#pragma unroll
      for (int r = 0; r < 4; ++r) p[cs][r] = __builtin_fmaf(p[cs][r], SC2, addn[cs][r]);

    // row max: in-register over 16 vals, then xor16/xor32 across lane-groups
    f32x4 t4;
#pragma unroll
    for (int r = 0; r < 4; ++r)
      t4[r] = fmaxf(fmaxf(p[0][r], p[1][r]), fmaxf(p[2][r], p[3][r]));
    float tm = fmaxf(fmaxf(t4[0], t4[1]), fmaxf(t4[2], t4[3]));
    tm = fmaxf(tm, __shfl_xor(tm, 16));
    tm = fmaxf(tm, __shfl_xor(tm, 32));
    float mnew = fmaxf(m2, tm);
    float corr = EXP2(m2 - mnew);
    m2 = mnew;

    // p = exp2(ppre - mnew); row sum
#pragma unroll
    for (int cs = 0; cs < 4; ++cs)
#pragma unroll
      for (int r = 0; r < 4; ++r) p[cs][r] = EXP2(p[cs][r] - mnew);
    f32x4 s4;
#pragma unroll
    for (int r = 0; r < 4; ++r) s4[r] = (p[0][r] + p[1][r]) + (p[2][r] + p[3][r]);
    float rsum = (s4[0] + s4[1]) + (s4[2] + s4[3]);
    rsum += __shfl_xor(rsum, 16);
    rsum += __shfl_xor(rsum, 32);
    l_r = __builtin_fmaf(l_r, corr, rsum);

#pragma unroll
    for (int ds_ = 0; ds_ < 4; ++ds_)
#pragma unroll
      for (int r = 0; r < 4; ++r) acc[ds_][r] *= corr;

    // P^T -> bf16 packed words: wd[cs][h] = (p[cs][2h], p[cs][2h+1])
    uint32_t wd[4][2];
#pragma unroll
    for (int cs = 0; cs < 4; ++cs)
#pragma unroll
      for (int hh = 0; hh < 2; ++hh)
        asm("v_cvt_pk_bf16_f32 %0, %1, %2" : "=v"(wd[cs][hh]) : "v"(p[cs][2 * hh]), "v"(p[cs][2 * hh + 1]));

    // permlane dance -> PV B-operand fragments: pf[chunk] holds P^T[k=chunk*32+lg*8+j][qrow]
    short8 pf[2];
#pragma unroll
    for (int c = 0; c < 2; ++c) {
      union { uint32_t u[4]; short8 s8; } cv;
#pragma unroll
      for (int hh = 0; hh < 2; ++hh) {
        uint32_t A = wd[2 * c][hh], B = wd[2 * c + 1][hh];
        asm("v_permlane32_swap_b32 %0, %1" : "+v"(A), "+v"(B));
        asm("v_permlane16_swap_b32 %0, %1" : "+v"(A), "+v"(B));
        cv.u[hh] = A;       // widx 0 (h=0) / 1 (h=1)
        cv.u[2 + hh] = B;   // widx 2 (h=0) / 3 (h=1)
      }
      pf[c] = cv.s8;
    }

    // O^T += V^T P^T
    __builtin_amdgcn_s_setprio(1);
#pragma unroll
    for (int ds_ = 0; ds_ < 4; ++ds_) {
      short8 vf0 = frag_read(lV[cur], ds_ * 16 + l15, lg);
      short8 vf1 = frag_read(lV[cur], ds_ * 16 + l15, 4 + lg);
      acc[ds_] = __builtin_amdgcn_mfma_f32_16x16x32_bf16(vf0, pf[0], acc[ds_], 0, 0, 0);
      acc[ds_] = __builtin_amdgcn_mfma_f32_16x16x32_bf16(vf1, pf[1], acc[ds_], 0, 0, 0);
    }
    __builtin_amdgcn_s_setprio(0);

    __syncthreads();  // drains vmcnt (stage t+1) + lgkmcnt; protects buffer reuse
    cur ^= 1;
  }

  // epilogue: attn_out[b, n=qrow, h*64 + d] = O^T[d][qrow] / l
  float inv = 1.0f / l_r;
  size_t base = ((size_t)b * NSEQ + qrow) * 384 + h * 64;
#pragma unroll
  for (int ds_ = 0; ds_ < 4; ++ds_) {
    uint32_t w0, w1;
    float a0 = acc[ds_][0] * inv, a1 = acc[ds_][1] * inv;
    float a2 = acc[ds_][2] * inv, a3 = acc[ds_][3] * inv;
    asm("v_cvt_pk_bf16_f32 %0, %1, %2" : "=v"(w0) : "v"(a0), "v"(a1));
    asm("v_cvt_pk_bf16_f32 %0, %1, %2" : "=v"(w1) : "v"(a2), "v"(a3));
    uint2 st; st.x = w0; st.y = w1;
    *(uint2*)(attn_out + base + ds_ * 16 + lg * 4) = st;
  }
#undef STAGE
}

extern "C" void kernel_launch(void* const* d_in, const int* in_sizes, int n_in,
                              void* d_out, int out_size, void* d_ws, size_t ws_size,
                              hipStream_t stream) {
  const float* x = (const float*)d_in[0];
  const int* mask = (const int*)d_in[1];
  const float* w_qkv = (const float*)d_in[2];
  const float* w_proj = (const float*)d_in[3];
  const float* b_proj = (const float*)d_in[4];
  float* out = (float*)d_out;

  char* ws = (char*)d_ws;
  u16* x_bf = (u16*)(ws + 0);              //  8192x384
  u16* wqkv_bf = (u16*)(ws + 6291456);     //  1152x384
  u16* wproj_bf = (u16*)(ws + 7176192);    //   384x384
  u16* q_bf = (u16*)(ws + 7471104);        //  [b,h,n,d]
  u16* k_bf = (u16*)(ws + 13762560);       //  [b,h,n,d]
  u16* vt_bf = (u16*)(ws + 20054016);      //  [b,h,d,n]
  u16* attn_bf = (u16*)(ws + 26345472);    //  8192x384

  cast_kernel<<<(3145728 / 8 + 255) / 256, 256, 0, stream>>>(x, x_bf, 3145728 / 8);
  cast_kernel<<<(442368 / 8 + 255) / 256, 256, 0, stream>>>(w_qkv, wqkv_bf, 442368 / 8);
  cast_kernel<<<(147456 / 8 + 255) / 256, 256, 0, stream>>>(w_proj, wproj_bf, 147456 / 8);

  gemm_bt<0><<<dim3(64, 9), 256, 0, stream>>>(x_bf, wqkv_bf, 384, 1152,
                                              q_bf, k_bf, vt_bf, nullptr, nullptr);
  attn_kernel<<<dim3(64, 12), 256, 0, stream>>>(q_bf, k_bf, vt_bf, mask, attn_bf);
  gemm_bt<1><<<dim3(64, 3), 256, 0, stream>>>(attn_bf, wproj_bf, 384, 384,
                                              nullptr, nullptr, nullptr, b_proj, out);
}

// Round 3
// 150.850 us; speedup vs baseline: 1.6717x; 1.0196x over previous
//
#include <hip/hip_runtime.h>
#include <cfloat>
#include <cstdint>
#include <cstddef>

using u16 = unsigned short;
typedef __attribute__((ext_vector_type(8))) short short8;
typedef __attribute__((ext_vector_type(4))) float f32x4;

#define HEADS 6
#define NSEQ 4096
#define SCALEF 0.125f
#define LOG2E 1.4426950408889634f
#define SC2 (SCALEF * LOG2E)

#if __has_builtin(__builtin_amdgcn_exp2f)
#define EXP2(x) __builtin_amdgcn_exp2f(x)
#else
#define EXP2(x) exp2f(x)
#endif

__device__ __forceinline__ f32x4 vmin4(f32x4 a, f32x4 b) {
#if __has_builtin(__builtin_elementwise_min)
  return __builtin_elementwise_min(a, b);
#else
  f32x4 r; for (int i = 0; i < 4; ++i) r[i] = fminf(a[i], b[i]); return r;
#endif
}
__device__ __forceinline__ f32x4 vmax4(f32x4 a, f32x4 b) {
#if __has_builtin(__builtin_elementwise_max)
  return __builtin_elementwise_max(a, b);
#else
  f32x4 r; for (int i = 0; i < 4; ++i) r[i] = fmaxf(a[i], b[i]); return r;
#endif
}

__device__ __forceinline__ u16 f2bf_rn(float f) {
  unsigned int u = __builtin_bit_cast(unsigned int, f);
  u = (u + 0x7FFFu + ((u >> 16) & 1u)) >> 16;
  return (u16)u;
}

__device__ __forceinline__ void gload_lds16(const void* g, void* l) {
  __builtin_amdgcn_global_load_lds((const __attribute__((address_space(1))) void*)g,
                                   (__attribute__((address_space(3))) void*)l, 16, 0, 0);
}

// Swizzled b128 read from a [rows][64] u16 LDS tile (128B rows).
__device__ __forceinline__ short8 frag_read(const u16* tile, int row, int blk) {
  int byt = row * 128 + ((blk * 16) ^ ((row & 7) << 4));
  return *(const short8*)((const char*)tile + byt);
}

__global__ void cast_kernel(const float* __restrict__ src, u16* __restrict__ dst, int n8) {
  int i = blockIdx.x * blockDim.x + threadIdx.x;
  if (i >= n8) return;
  const float4* s = (const float4*)src;
  float4 a = s[2 * i], b = s[2 * i + 1];
  short8 r;
  r[0] = (short)f2bf_rn(a.x); r[1] = (short)f2bf_rn(a.y);
  r[2] = (short)f2bf_rn(a.z); r[3] = (short)f2bf_rn(a.w);
  r[4] = (short)f2bf_rn(b.x); r[5] = (short)f2bf_rn(b.y);
  r[6] = (short)f2bf_rn(b.z); r[7] = (short)f2bf_rn(b.w);
  ((short8*)dst)[i] = r;
}

__global__ void mask_addend_kernel(const int* __restrict__ m, float* __restrict__ out, int n) {
  int i = blockIdx.x * blockDim.x + threadIdx.x;
  if (i < n) out[i] = m[i] ? 0.f : -FLT_MAX;
}

// C = A(MxK) * B(NxK)^T ; 128x128 tile, BK=64, 4 waves (2x2 of 64x64).
template <int EPI>
__launch_bounds__(256)
__global__ void gemm_bt(const u16* __restrict__ A, const u16* __restrict__ B,
                        int Kdim, int Ndim,
                        u16* __restrict__ q_out, u16* __restrict__ k_out, u16* __restrict__ vt_out,
                        const float* __restrict__ bias, float* __restrict__ out) {
  __shared__ u16 lA[128 * 64];
  __shared__ u16 lB[128 * 64];
  int brow = blockIdx.x, bcol = blockIdx.y;
  int tid = threadIdx.x;
  int w = tid >> 6, lane = tid & 63;
  int wr = w >> 1, wc = w & 1;
  int r_in = lane >> 3;
  int jblk = (lane & 7) ^ r_in;
  int l15 = lane & 15, lg = lane >> 4;

  f32x4 acc[4][4];
#pragma unroll
  for (int i = 0; i < 4; i++)
#pragma unroll
    for (int j = 0; j < 4; j++) acc[i][j] = (f32x4){0.f, 0.f, 0.f, 0.f};

  const u16* Ab = A + (size_t)(brow * 128 + w * 32 + r_in) * Kdim + jblk * 8;
  const u16* Bb = B + (size_t)(bcol * 128 + w * 32 + r_in) * Kdim + jblk * 8;

  int ksteps = Kdim >> 6;
  for (int kt = 0; kt < ksteps; ++kt) {
    __syncthreads();
#pragma unroll
    for (int c = 0; c < 4; ++c) {
      gload_lds16(Ab + kt * 64 + (size_t)(c * 8) * Kdim, &lA[(w * 32 + c * 8) * 64]);
      gload_lds16(Bb + kt * 64 + (size_t)(c * 8) * Kdim, &lB[(w * 32 + c * 8) * 64]);
    }
    asm volatile("s_waitcnt vmcnt(0)" ::: "memory");
    __syncthreads();

    short8 af[4][2], bfr[4][2];
#pragma unroll
    for (int ms = 0; ms < 4; ++ms)
#pragma unroll
      for (int hf = 0; hf < 2; ++hf)
        af[ms][hf] = frag_read(lA, wr * 64 + ms * 16 + l15, hf * 4 + lg);
#pragma unroll
    for (int ns = 0; ns < 4; ++ns)
#pragma unroll
      for (int hf = 0; hf < 2; ++hf)
        bfr[ns][hf] = frag_read(lB, wc * 64 + ns * 16 + l15, hf * 4 + lg);
#pragma unroll
    for (int ms = 0; ms < 4; ++ms)
#pragma unroll
      for (int ns = 0; ns < 4; ++ns) {
        acc[ms][ns] = __builtin_amdgcn_mfma_f32_16x16x32_bf16(af[ms][0], bfr[ns][0], acc[ms][ns], 0, 0, 0);
        acc[ms][ns] = __builtin_amdgcn_mfma_f32_16x16x32_bf16(af[ms][1], bfr[ns][1], acc[ms][ns], 0, 0, 0);
      }
  }

#pragma unroll
  for (int ms = 0; ms < 4; ++ms)
#pragma unroll
    for (int ns = 0; ns < 4; ++ns)
#pragma unroll
      for (int r = 0; r < 4; ++r) {
        int row_g = brow * 128 + wr * 64 + ms * 16 + lg * 4 + r;
        int col_g = bcol * 128 + wc * 64 + ns * 16 + l15;
        float v = acc[ms][ns][r];
        if (EPI == 0) {
          int t = col_g / 384;
          int rem = col_g - t * 384;
          int h = rem >> 6, d = rem & 63;
          int b = row_g >> 12, n = row_g & 4095;
          u16 val = f2bf_rn(v);
          size_t bh = (size_t)(b * HEADS + h);
          if (t == 0)      q_out[(bh * NSEQ + n) * 64 + d] = val;
          else if (t == 1) k_out[(bh * NSEQ + n) * 64 + d] = val;
          else             vt_out[(bh * 64 + d) * NSEQ + n] = val;
        } else {
          out[(size_t)row_g * Ndim + col_g] = v + bias[col_g];
        }
      }
}

// Flash attention, swapped-operand: 256 thr = 4 waves x 16 q-rows, KT=64.
// VALU-lean: packed-f32 softmax, defer-rescale (THR=8), immediate-folded LDS reads.
__launch_bounds__(256, 3)
__global__ void attn_kernel(const u16* __restrict__ qg, const u16* __restrict__ kg,
                            const u16* __restrict__ vtg, const float* __restrict__ madd,
                            u16* __restrict__ attn_out) {
  __shared__ u16 lK[2][64 * 64];   // [k_seq][d], swizzled
  __shared__ u16 lV[2][64 * 64];   // [d][k_seq], swizzled

  // bijective XCD swizzle: 768 blocks, 96 per XCD, contiguous bh-major work per XCD
  int bid = blockIdx.y * 64 + blockIdx.x;
  int orig = (bid & 7) * 96 + (bid >> 3);
  int qb = orig & 63, bh = orig >> 6;

  int b = bh / HEADS, h = bh - b * HEADS;
  int q0 = qb * 64;
  int tid = threadIdx.x;
  int w = tid >> 6, lane = tid & 63;
  int l15 = lane & 15, lg = lane >> 4;
  int r_in = lane >> 3, jblk = (lane & 7) ^ r_in;

  const u16* Q = qg + (size_t)bh * NSEQ * 64;
  const u16* K = kg + (size_t)bh * NSEQ * 64;
  const u16* VT = vtg + (size_t)bh * 64 * NSEQ;
  const float* marow = madd + b * NSEQ;

  int qrow = q0 + w * 16 + l15;
  short8 qf[2];
#pragma unroll
  for (int hf = 0; hf < 2; ++hf)
    qf[hf] = *(const short8*)(Q + (size_t)qrow * 64 + hf * 32 + lg * 8);

  float aqf = marow[qrow];                       // 0 or -FLT_MAX
  f32x4 aqf4 = (f32x4){aqf, aqf, aqf, aqf};

  // lane-constant swizzled offsets: row = cs*16 + l15 -> row&7 == l15&7
  int sw = (l15 & 7) << 4;
  int offA = l15 * 128 + ((lg * 16) ^ sw);
  int offB = l15 * 128 + (((4 + lg) * 16) ^ sw);

  f32x4 acc[4];  // O^T: acc[ds][r] = O[d = ds*16 + lg*4 + r][q = qrow]
#pragma unroll
  for (int ds_ = 0; ds_ < 4; ++ds_) acc[ds_] = (f32x4){0.f, 0.f, 0.f, 0.f};
  float m2 = -INFINITY, l_r = 0.f;

#define STAGE(buf, t)                                                                   \
  {                                                                                     \
    int k0s = (t) * 64;                                                                 \
    _Pragma("unroll")                                                                   \
    for (int c = 0; c < 2; ++c) {                                                       \
      int rowb = w * 16 + c * 8;                                                        \
      gload_lds16(K + (size_t)(k0s + rowb + r_in) * 64 + jblk * 8, &lK[buf][rowb * 64]);\
      gload_lds16(VT + (size_t)(rowb + r_in) * NSEQ + k0s + jblk * 8, &lV[buf][rowb * 64]);\
    }                                                                                   \
  }

  STAGE(0, 0);
  __syncthreads();

  const int NT = NSEQ / 64;
  int cur = 0;
  for (int t = 0; t < NT; ++t) {
    if (t + 1 < NT) STAGE(cur ^ 1, t + 1);
    int k0 = t * 64;

    const char* kbA = (const char*)lK[cur] + offA;
    const char* kbB = (const char*)lK[cur] + offB;

    // mask addend (packed min vs lane's q-addend)
    f32x4 addn[4];
#pragma unroll
    for (int cs = 0; cs < 4; ++cs) {
      f32x4 mf = *(const f32x4*)(marow + k0 + cs * 16 + lg * 4);
      addn[cs] = vmin4(mf, aqf4);
    }

    // S^T = K Q^T : p[cs][r] = S[q = qrow][k = k0 + cs*16 + lg*4 + r]
    f32x4 p[4];
    __builtin_amdgcn_s_setprio(1);
#pragma unroll
    for (int cs = 0; cs < 4; ++cs) {
      short8 kf0 = *(const short8*)(kbA + cs * 2048);
      short8 kf1 = *(const short8*)(kbB + cs * 2048);
      f32x4 z = (f32x4){0.f, 0.f, 0.f, 0.f};
      z = __builtin_amdgcn_mfma_f32_16x16x32_bf16(kf0, qf[0], z, 0, 0, 0);
      p[cs] = __builtin_amdgcn_mfma_f32_16x16x32_bf16(kf1, qf[1], z, 0, 0, 0);
    }
    __builtin_amdgcn_s_setprio(0);

    // log2-space pre-softmax (packed fma)
#pragma unroll
    for (int cs = 0; cs < 4; ++cs) p[cs] = p[cs] * SC2 + addn[cs];

    // row max: packed tree + 2 shuffles
    f32x4 t4 = vmax4(vmax4(p[0], p[1]), vmax4(p[2], p[3]));
    float tm = fmaxf(fmaxf(t4[0], t4[1]), fmaxf(t4[2], t4[3]));
    tm = fmaxf(tm, __shfl_xor(tm, 16));
    tm = fmaxf(tm, __shfl_xor(tm, 32));

    // T13 defer-rescale: only rescale when some lane grew past THR=8
    if (!__all(tm <= m2 + 8.0f)) {
      float mnew = fmaxf(m2, tm);
      float corr = EXP2(m2 - mnew);
      m2 = mnew;
      l_r *= corr;
#pragma unroll
      for (int ds_ = 0; ds_ < 4; ++ds_) acc[ds_] *= corr;
    }

    // p = exp2(p - m2); packed sub, scalar exp2
#pragma unroll
    for (int cs = 0; cs < 4; ++cs) {
      f32x4 d = p[cs] - m2;
#pragma unroll
      for (int r = 0; r < 4; ++r) p[cs][r] = EXP2(d[r]);
    }
    f32x4 s4 = (p[0] + p[1]) + (p[2] + p[3]);
    float rsum = (s4[0] + s4[1]) + (s4[2] + s4[3]);
    rsum += __shfl_xor(rsum, 16);
    rsum += __shfl_xor(rsum, 32);
    l_r += rsum;

    // P^T -> bf16 packed words: wd[cs][h] = (p[cs][2h], p[cs][2h+1])
    uint32_t wd[4][2];
#pragma unroll
    for (int cs = 0; cs < 4; ++cs)
#pragma unroll
      for (int hh = 0; hh < 2; ++hh)
        asm("v_cvt_pk_bf16_f32 %0, %1, %2" : "=v"(wd[cs][hh]) : "v"(p[cs][2 * hh]), "v"(p[cs][2 * hh + 1]));

    // permlane dance -> PV B-operand fragments
    short8 pf[2];
#pragma unroll
    for (int c = 0; c < 2; ++c) {
      union { uint32_t u[4]; short8 s8; } cv;
#pragma unroll
      for (int hh = 0; hh < 2; ++hh) {
        uint32_t A = wd[2 * c][hh], B = wd[2 * c + 1][hh];
        asm("v_permlane32_swap_b32 %0, %1" : "+v"(A), "+v"(B));
        asm("v_permlane16_swap_b32 %0, %1" : "+v"(A), "+v"(B));
        cv.u[hh] = A;
        cv.u[2 + hh] = B;
      }
      pf[c] = cv.s8;
    }

    // O^T += V^T P^T
    const char* vbA = (const char*)lV[cur] + offA;
    const char* vbB = (const char*)lV[cur] + offB;
    __builtin_amdgcn_s_setprio(1);
#pragma unroll
    for (int ds_ = 0; ds_ < 4; ++ds_) {
      short8 vf0 = *(const short8*)(vbA + ds_ * 2048);
      short8 vf1 = *(const short8*)(vbB + ds_ * 2048);
      acc[ds_] = __builtin_amdgcn_mfma_f32_16x16x32_bf16(vf0, pf[0], acc[ds_], 0, 0, 0);
      acc[ds_] = __builtin_amdgcn_mfma_f32_16x16x32_bf16(vf1, pf[1], acc[ds_], 0, 0, 0);
    }
    __builtin_amdgcn_s_setprio(0);

    __syncthreads();  // drains vmcnt (stage t+1) + lgkmcnt; protects buffer reuse
    cur ^= 1;
  }

  // epilogue: attn_out[b, n=qrow, h*64 + d] = O^T[d][qrow] / l
  float inv = 1.0f / l_r;
  size_t base = ((size_t)b * NSEQ + qrow) * 384 + h * 64;
#pragma unroll
  for (int ds_ = 0; ds_ < 4; ++ds_) {
    uint32_t w0, w1;
    float a0 = acc[ds_][0] * inv, a1 = acc[ds_][1] * inv;
    float a2 = acc[ds_][2] * inv, a3 = acc[ds_][3] * inv;
    asm("v_cvt_pk_bf16_f32 %0, %1, %2" : "=v"(w0) : "v"(a0), "v"(a1));
    asm("v_cvt_pk_bf16_f32 %0, %1, %2" : "=v"(w1) : "v"(a2), "v"(a3));
    uint2 st; st.x = w0; st.y = w1;
    *(uint2*)(attn_out + base + ds_ * 16 + lg * 4) = st;
  }
#undef STAGE
}

extern "C" void kernel_launch(void* const* d_in, const int* in_sizes, int n_in,
                              void* d_out, int out_size, void* d_ws, size_t ws_size,
                              hipStream_t stream) {
  const float* x = (const float*)d_in[0];
  const int* mask = (const int*)d_in[1];
  const float* w_qkv = (const float*)d_in[2];
  const float* w_proj = (const float*)d_in[3];
  const float* b_proj = (const float*)d_in[4];
  float* out = (float*)d_out;

  char* ws = (char*)d_ws;
  u16* x_bf = (u16*)(ws + 0);              //  8192x384
  u16* wqkv_bf = (u16*)(ws + 6291456);     //  1152x384
  u16* wproj_bf = (u16*)(ws + 7176192);    //   384x384
  u16* q_bf = (u16*)(ws + 7471104);        //  [b,h,n,d]
  u16* k_bf = (u16*)(ws + 13762560);       //  [b,h,n,d]
  u16* vt_bf = (u16*)(ws + 20054016);      //  [b,h,d,n]
  u16* attn_bf = (u16*)(ws + 26345472);    //  8192x384
  float* madd = (float*)(ws + 32636928);   //  [2][4096] f32

  cast_kernel<<<(3145728 / 8 + 255) / 256, 256, 0, stream>>>(x, x_bf, 3145728 / 8);
  cast_kernel<<<(442368 / 8 + 255) / 256, 256, 0, stream>>>(w_qkv, wqkv_bf, 442368 / 8);
  cast_kernel<<<(147456 / 8 + 255) / 256, 256, 0, stream>>>(w_proj, wproj_bf, 147456 / 8);
  mask_addend_kernel<<<32, 256, 0, stream>>>(mask, madd, 2 * NSEQ);

  gemm_bt<0><<<dim3(64, 9), 256, 0, stream>>>(x_bf, wqkv_bf, 384, 1152,
                                              q_bf, k_bf, vt_bf, nullptr, nullptr);
  attn_kernel<<<dim3(64, 12), 256, 0, stream>>>(q_bf, k_bf, vt_bf, madd, attn_bf);
  gemm_bt<1><<<dim3(64, 3), 256, 0, stream>>>(attn_bf, wproj_bf, 384, 384,
                                              nullptr, nullptr, nullptr, b_proj, out);
}